// Round 4
// baseline (251.022 us; speedup 1.0000x reference)
//
#include <hip/hip_runtime.h>
#include <hip/hip_bf16.h>
#include <math.h>

#define HH 128
#define WW 128
#define HWSZ (HH*WW)

typedef __attribute__((ext_vector_type(8))) short bfrag;   // 8 bf16
typedef __attribute__((ext_vector_type(4))) float f4;

__device__ inline unsigned short f2bf(float v) {
    unsigned u = __builtin_bit_cast(unsigned, v);
    unsigned r = u + 0x7fffu + ((u >> 16) & 1u);
    return (unsigned short)(r >> 16);
}
__device__ inline float bf2f(short s) {
    return __builtin_bit_cast(float, ((unsigned)(unsigned short)s) << 16);
}
__device__ inline float bf2f_lo(unsigned u) { return __builtin_bit_cast(float, u << 16); }
__device__ inline float bf2f_hi(unsigned u) { return __builtin_bit_cast(float, u & 0xffff0000u); }

// ---------------------------------------------------------------------------
// Weight prepack: fp32 W[oc][ic][3][3] -> bf16 A-fragments, K-chunk = 32.
// frag f = ((oct*(NIC/32) + c32)*9 + tap); element = f*512 + lane*8 + j
// oc = oct*16 + (lane&15); ic = c32*32 + (lane>>4)*8 + j
// ---------------------------------------------------------------------------
__device__ inline void pack_frag(const float* __restrict__ w, short* __restrict__ dst,
                                 int i, int NIC, int NOC) {
    int j    = i & 7;
    int lane = (i >> 3) & 63;
    int f    = i >> 9;
    int tap  = f % 9;
    int g    = f / 9;
    int NCH  = NIC >> 5;
    int c32  = g % NCH;
    int oct  = g / NCH;
    int oc   = oct * 16 + (lane & 15);
    int ic   = c32 * 32 + ((lane >> 4) & 3) * 8 + j;
    float v = 0.f;
    if (oc < NOC) v = w[((size_t)oc * NIC + ic) * 9 + tap];
    dst[i] = (short)f2bf(v);
}

#define SZ128 73728
#define SZ64  36864

__global__ void pack_all_k(const float* __restrict__ w1, const float* __restrict__ w2,
                           const float* __restrict__ w3, const float* __restrict__ wom,
                           const float* __restrict__ wout, const float* __restrict__ wdcn,
                           short* __restrict__ ap)
{
    int i = blockIdx.x * 256 + threadIdx.x;
    if      (i < SZ128)                  pack_frag(w1,  ap,                          i,                    128, 64);
    else if (i < 2*SZ128)                pack_frag(w2,  ap + SZ128,                  i - SZ128,            128, 64);
    else if (i < 2*SZ128 + SZ64)         pack_frag(w3,  ap + 2*SZ128,                i - 2*SZ128,           64, 64);
    else if (i < 2*SZ128 + 2*SZ64)       pack_frag(wom, ap + 2*SZ128 + SZ64,         i - 2*SZ128 - SZ64,    64, 27);
    else if (i < 2*SZ128 + 3*SZ64)       pack_frag(wout,ap + 2*SZ128 + 2*SZ64,       i - 2*SZ128 - 2*SZ64,  64, 64);
    else if (i < 2*SZ128 + 4*SZ64)       pack_frag(wdcn,ap + 2*SZ128 + 3*SZ64,       i - 2*SZ128 - 3*SZ64,  64, 64);
}

// ---------------------------------------------------------------------------
// NCHW fp32 -> NHWC bf16 (stride 64), all 3 input tensors in one dispatch.
// ---------------------------------------------------------------------------
__global__ __launch_bounds__(256) void nhwc3_k(const float* __restrict__ x,
                                               const float* __restrict__ xng,
                                               const float* __restrict__ offt,
                                               short* __restrict__ dx,
                                               short* __restrict__ dn,
                                               short* __restrict__ dof)
{
    __shared__ short s_t[128][72];
    const int tid = threadIdx.x;
    const int h = blockIdx.x;
    const int t = blockIdx.y >> 2, b = blockIdx.y & 3;
    const float* src = (t == 0) ? x : (t == 1) ? xng : offt;
    short* dst = (t == 0) ? dx : (t == 1) ? dn : dof;
    for (int i = tid; i < 64 * 128; i += 256) {
        int c = i >> 7, w = i & 127;
        s_t[w][c] = (short)f2bf(src[((size_t)(b * 64 + c)) * HWSZ + h * WW + w]);
    }
    __syncthreads();
    for (int i = tid; i < 128 * 32; i += 256) {
        int w = i >> 5, cp = i & 31;
        unsigned pk = (unsigned)(unsigned short)s_t[w][cp * 2]
                    | ((unsigned)(unsigned short)s_t[w][cp * 2 + 1] << 16);
        *(unsigned*)&dst[(((size_t)(b * 128 + h) * 128 + w) * 64) + cp * 2] = pk;
    }
}

// ---------------------------------------------------------------------------
// MFMA implicit-GEMM 3x3 SAME conv over NHWC bf16, K-chunk = 32.
// R9: R0 harness-verified structure, byte-for-byte (249 us pass).
// block = one (b,h) row, 4 waves = 2 oc-halves x 2 px-halves.
// ---------------------------------------------------------------------------
template<int NIC, int NOC, int OCS, int ACT, bool WH, bool WC>
__global__ __launch_bounds__(256, 3) void conv_k(
    const short* __restrict__ in1, const short* __restrict__ in2,
    const short* __restrict__ apack, const float* __restrict__ bias,
    short* __restrict__ outh, float* __restrict__ outc)
{
    constexpr int NCH = NIC / 32;
    __shared__ short s_x[3][130][40];   // [row][px+halo][32ch + pad]

    const int tid  = threadIdx.x;
    const int lane = tid & 63;
    const int wv   = tid >> 6;
    const int wo   = wv & 1;
    const int wp   = wv >> 1;
    const int n16  = lane & 15;
    const int kq   = lane >> 4;

    const int lin = blockIdx.x;                       // 512 blocks
    const int h   = (lin & 7) * 16 + ((lin >> 3) & 15);
    const int b   = lin >> 7;

    f4 acc[2][4];
#pragma unroll
    for (int t = 0; t < 2; ++t)
#pragma unroll
        for (int p = 0; p < 4; ++p) acc[t][p] = (f4){0.f, 0.f, 0.f, 0.f};

    const short* a_lane = apack + (size_t)lane * 8;

    for (int cc = 0; cc < NCH; ++cc) {
        const short* src; int c0;
        if (NIC == 128 && cc >= 2) { src = in2; c0 = (cc - 2) * 32; }
        else                       { src = in1; c0 = cc * 32; }
        __syncthreads();
        // stage 3 rows x 130 px x 32 ch, 16B per thread-iter (R5 verbatim)
        for (int i = tid; i < 1560; i += 256) {
            int row = i / 520, rem = i % 520;
            int px = rem >> 2, q = rem & 3;
            int gy = h - 1 + row, gx = px - 1;
            int4 v = {0, 0, 0, 0};
            if ((unsigned)gy < 128u && (unsigned)gx < 128u)
                v = *(const int4*)&src[(((size_t)(b * 128 + gy)) * 128 + gx) * 64 + c0 + q * 8];
            *(int4*)&s_x[row][px][q * 8] = v;
        }
        __syncthreads();

        if (wo * 32 < NOC) {
            // all-tap A prefetch: 18 independent global loads issued upfront
            bfrag af0[9], af1[9];
#pragma unroll
            for (int tap = 0; tap < 9; ++tap) {
                af0[tap] = *(const bfrag*)(a_lane + (size_t)(((wo * 2 + 0) * NCH + cc) * 9 + tap) * 512);
                af1[tap] = *(const bfrag*)(a_lane + (size_t)(((wo * 2 + 1) * NCH + cc) * 9 + tap) * 512);
            }
#pragma unroll
            for (int tap = 0; tap < 9; ++tap) {
                const int dy = tap / 3, dx = tap % 3;
#pragma unroll
                for (int p = 0; p < 4; ++p) {
                    bfrag bb = *(const bfrag*)&s_x[dy][wp * 64 + p * 16 + n16 + dx][kq * 8];
                    acc[0][p] = __builtin_amdgcn_mfma_f32_16x16x32_bf16(af0[tap], bb, acc[0][p], 0, 0, 0);
                    acc[1][p] = __builtin_amdgcn_mfma_f32_16x16x32_bf16(af1[tap], bb, acc[1][p], 0, 0, 0);
                }
            }
        }
    }

    // epilogue: C/D layout col=lane&15, row=(lane>>4)*4+reg (R5 verbatim)
#pragma unroll
    for (int oct = 0; oct < 2; ++oct) {
        int oc0 = wo * 32 + oct * 16 + kq * 4;
        if (oc0 < NOC) {
            float4 bv = *(const float4*)&bias[oc0];
#pragma unroll
            for (int p = 0; p < 4; ++p) {
                int col = wp * 64 + p * 16 + n16;
                float v0 = acc[oct][p][0] + bv.x;
                float v1 = acc[oct][p][1] + bv.y;
                float v2 = acc[oct][p][2] + bv.z;
                float v3 = acc[oct][p][3] + bv.w;
                if (ACT == 1) {
                    v0 = (v0 >= 0.f) ? v0 : 0.1f * v0;
                    v1 = (v1 >= 0.f) ? v1 : 0.1f * v1;
                    v2 = (v2 >= 0.f) ? v2 : 0.1f * v2;
                    v3 = (v3 >= 0.f) ? v3 : 0.1f * v3;
                }
                if (ACT == 2) {
                    v0 = fmaxf(v0, 0.f); v1 = fmaxf(v1, 0.f);
                    v2 = fmaxf(v2, 0.f); v3 = fmaxf(v3, 0.f);
                }
                if (WH) {
                    uint2 pk;
                    pk.x = (unsigned)f2bf(v0) | ((unsigned)f2bf(v1) << 16);
                    pk.y = (unsigned)f2bf(v2) | ((unsigned)f2bf(v3) << 16);
                    *(uint2*)&outh[(((size_t)(b * 128 + h)) * 128 + col) * OCS + oc0] = pk;
                }
                if (WC) {
                    size_t base = ((size_t)b * NOC) * HWSZ + h * WW + col;
                    outc[base + (size_t)(oc0 + 0) * HWSZ] = v0;
                    outc[base + (size_t)(oc0 + 1) * HWSZ] = v1;
                    outc[base + (size_t)(oc0 + 2) * HWSZ] = v2;
                    outc[base + (size_t)(oc0 + 3) * HWSZ] = v3;
                }
            }
        }
    }
}

// ---------------------------------------------------------------------------
// DCN per-pixel bilinear params from NHWC bf16 om (stride 32), once per px.
// (R0 verbatim)
// ---------------------------------------------------------------------------
__device__ inline void dcn_params(const short* __restrict__ omb, int h, int k, int tid,
                                  float (*s_pw)[4], int (*s_pi)[4])
{
    if (tid < 128) {
        int pix = tid;
        const short* o = omb + pix * 32;
        float oy = bf2f(o[k]);
        float ox = bf2f(o[9 + k]);
        float mv = bf2f(o[18 + k]);
        mv = 1.f / (1.f + expf(-mv));
        float py = (float)(h - 1 + (k / 3)) + oy;
        float px = (float)(pix - 1 + (k % 3)) + ox;
        float y0f = floorf(py), x0f = floorf(px);
        float ly = py - y0f, lx = px - x0f;
        int y0 = (int)y0f, x0 = (int)x0f;
        int y1 = y0 + 1, x1 = x0 + 1;
        float v00 = ((unsigned)y0 < 128u && (unsigned)x0 < 128u) ? 1.f : 0.f;
        float v01 = ((unsigned)y0 < 128u && (unsigned)x1 < 128u) ? 1.f : 0.f;
        float v10 = ((unsigned)y1 < 128u && (unsigned)x0 < 128u) ? 1.f : 0.f;
        float v11 = ((unsigned)y1 < 128u && (unsigned)x1 < 128u) ? 1.f : 0.f;
        int yc0 = min(max(y0, 0), 127), yc1 = min(max(y1, 0), 127);
        int xc0 = min(max(x0, 0), 127), xc1 = min(max(x1, 0), 127);
        s_pw[pix][0] = (1.f - ly) * (1.f - lx) * mv * v00;
        s_pw[pix][1] = (1.f - ly) * lx * mv * v01;
        s_pw[pix][2] = ly * (1.f - lx) * mv * v10;
        s_pw[pix][3] = ly * lx * mv * v11;
        s_pi[pix][0] = (yc0 * WW + xc0) * 64;
        s_pi[pix][1] = (yc0 * WW + xc1) * 64;
        s_pi[pix][2] = (yc1 * WW + xc0) * 64;
        s_pi[pix][3] = (yc1 * WW + xc1) * 64;
    }
}

// ---------------------------------------------------------------------------
// MFMA DCN (R0 structure: block = full row, 256 thr, wo x wp waves).
// XCD-swizzled grid (512); rolling-1 A-fragment prefetch. R0 verbatim.
// ---------------------------------------------------------------------------
__global__ __launch_bounds__(256, 4) void dcn_k(
    const short* __restrict__ xt, const short* __restrict__ om,
    const short* __restrict__ adcn, const float* __restrict__ bias,
    short* __restrict__ outh)
{
    __shared__ short s_samp[128][72];
    __shared__ float s_pw[128][4];
    __shared__ int   s_pi[128][4];

    const int tid  = threadIdx.x;
    const int lane = tid & 63;
    const int wv   = tid >> 6;
    const int wo   = wv & 1;
    const int wp   = wv >> 1;
    const int n16  = lane & 15;
    const int kq   = lane >> 4;

    const int lin = blockIdx.x;                       // 512 blocks
    const int h   = (lin & 7) * 16 + ((lin >> 3) & 15);
    const int b   = lin >> 7;

    f4 acc[2][4];
#pragma unroll
    for (int t = 0; t < 2; ++t)
#pragma unroll
        for (int p = 0; p < 4; ++p) acc[t][p] = (f4){0.f, 0.f, 0.f, 0.f};

    const short* a_lane = adcn + (size_t)lane * 8;
    const short* xb  = xt + (size_t)b * HWSZ * 64;
    const short* omb = om + ((size_t)(b * 128 + h)) * 128 * 32;

    dcn_params(omb, h, 0, tid, s_pw, s_pi);

    const int pp = lane >> 5;      // pixel-pair half
    const int cp = lane & 31;      // channel pair

    bfrag a_cur[2][2], a_nxt[2][2];      // [oi][ks]
#pragma unroll
    for (int oi = 0; oi < 2; ++oi)
#pragma unroll
        for (int ks = 0; ks < 2; ++ks)
            a_cur[oi][ks] = *(const bfrag*)(a_lane +
                (size_t)(((wo * 2 + oi) * 2 + ks) * 9 + 0) * 512);

    for (int k = 0; k < 9; ++k) {
        __syncthreads();   // params(k) visible; MFMA(k-1) done with s_samp
#pragma unroll 4
        for (int i = 0; i < 16; ++i) {
            int pix = i * 8 + wv * 2 + pp;
            float4 w = *(const float4*)s_pw[pix];
            int4  ix = *(const int4*)s_pi[pix];
            unsigned u00 = *(const unsigned*)&xb[ix.x + cp * 2];
            unsigned u01 = *(const unsigned*)&xb[ix.y + cp * 2];
            unsigned u10 = *(const unsigned*)&xb[ix.z + cp * 2];
            unsigned u11 = *(const unsigned*)&xb[ix.w + cp * 2];
            float lo = w.x * bf2f_lo(u00) + w.y * bf2f_lo(u01) + w.z * bf2f_lo(u10) + w.w * bf2f_lo(u11);
            float hi = w.x * bf2f_hi(u00) + w.y * bf2f_hi(u01) + w.z * bf2f_hi(u10) + w.w * bf2f_hi(u11);
            *(unsigned*)&s_samp[pix][cp * 2] = (unsigned)f2bf(lo) | ((unsigned)f2bf(hi) << 16);
        }
        __syncthreads();
        if (k < 8) {
            dcn_params(omb, h, k + 1, tid, s_pw, s_pi);
#pragma unroll
            for (int oi = 0; oi < 2; ++oi)
#pragma unroll
                for (int ks = 0; ks < 2; ++ks)
                    a_nxt[oi][ks] = *(const bfrag*)(a_lane +
                        (size_t)(((wo * 2 + oi) * 2 + ks) * 9 + (k + 1)) * 512);
        }
#pragma unroll
        for (int ks = 0; ks < 2; ++ks) {
#pragma unroll
            for (int p = 0; p < 4; ++p) {
                bfrag bb = *(const bfrag*)&s_samp[wp * 64 + p * 16 + n16][ks * 32 + kq * 8];
                acc[0][p] = __builtin_amdgcn_mfma_f32_16x16x32_bf16(a_cur[0][ks], bb, acc[0][p], 0, 0, 0);
                acc[1][p] = __builtin_amdgcn_mfma_f32_16x16x32_bf16(a_cur[1][ks], bb, acc[1][p], 0, 0, 0);
            }
        }
#pragma unroll
        for (int oi = 0; oi < 2; ++oi)
#pragma unroll
            for (int ks = 0; ks < 2; ++ks)
                a_cur[oi][ks] = a_nxt[oi][ks];
    }

    // epilogue: NHWC bf16, stride 64, no activation (R0 verbatim)
#pragma unroll
    for (int oct = 0; oct < 2; ++oct) {
        int oc0 = wo * 32 + oct * 16 + kq * 4;
        float4 bv = *(const float4*)&bias[oc0];
#pragma unroll
        for (int p = 0; p < 4; ++p) {
            int col = wp * 64 + p * 16 + n16;
            uint2 pk;
            pk.x = (unsigned)f2bf(acc[oct][p][0] + bv.x) | ((unsigned)f2bf(acc[oct][p][1] + bv.y) << 16);
            pk.y = (unsigned)f2bf(acc[oct][p][2] + bv.z) | ((unsigned)f2bf(acc[oct][p][3] + bv.w) << 16);
            *(uint2*)&outh[(((size_t)(b * 128 + h)) * 128 + col) * 64 + oc0] = pk;
        }
    }
}

// ---------------------------------------------------------------------------
extern "C" void kernel_launch(void* const* d_in, const int* in_sizes, int n_in,
                              void* d_out, int out_size, void* d_ws, size_t ws_size,
                              hipStream_t stream)
{
    const float* x      = (const float*)d_in[0];
    const float* xng    = (const float*)d_in[1];
    const float* offt   = (const float*)d_in[2];
    const float* w1     = (const float*)d_in[3];
    const float* b1     = (const float*)d_in[4];
    const float* w2     = (const float*)d_in[5];
    const float* b2     = (const float*)d_in[6];
    const float* w3     = (const float*)d_in[7];
    const float* b3     = (const float*)d_in[8];
    const float* wom    = (const float*)d_in[9];
    const float* bom    = (const float*)d_in[10];
    const float* wdcn   = (const float*)d_in[11];
    const float* bdcn   = (const float*)d_in[12];
    const float* wout   = (const float*)d_in[13];
    const float* bout   = (const float*)d_in[14];

    float* out0 = (float*)d_out;
    float* out1 = out0 + (size_t)4 * 64 * HWSZ;

    const size_t NB = (size_t)4 * HWSZ * 64;   // elements per NHWC bf16 tensor
    short* xtx = (short*)d_ws;        // x NHWC (conv1 + dcn)
    short* xtn = xtx + NB;            // x_neigh NHWC -> later o2 -> later align
    short* xto = xtn + NB;            // offset_t NHWC -> later om (stride 32)
    short* o1  = xto + NB;            // offset_1 -> later o3
    short* apk = o1 + NB;

    short* o2    = xtn;
    short* o3    = o1;
    short* omb   = xto;
    short* align = xtn;

    short* a1p  = apk;
    short* a2p  = apk + SZ128;
    short* a3p  = apk + 2 * SZ128;
    short* aomp = apk + 2 * SZ128 + SZ64;
    short* aout = apk + 2 * SZ128 + 2 * SZ64;
    short* adcn = apk + 2 * SZ128 + 3 * SZ64;

    pack_all_k<<<(2 * SZ128 + 4 * SZ64 + 255) / 256, 256, 0, stream>>>(
        w1, w2, w3, wom, wout, wdcn, apk);
    nhwc3_k<<<dim3(HH, 12), 256, 0, stream>>>(x, xng, offt, xtx, xtn, xto);

    // offset_1 = lrelu(conv(cat(x, x_neigh)))
    conv_k<128, 64, 64, 1, true, false><<<512, 256, 0, stream>>>(xtx, xtn, a1p, b1, o1, nullptr);
    // offset_2 = lrelu(conv(cat(offset_1, offset_t)))
    conv_k<128, 64, 64, 1, true, false><<<512, 256, 0, stream>>>(o1, xto, a2p, b2, o2, nullptr);
    // offset = lrelu(conv(offset_2)) -> NHWC for conv4 + NCHW fp32 output 1
    conv_k<64, 64, 64, 1, true, true><<<512, 256, 0, stream>>>(o2, nullptr, a3p, b3, o3, out1);
    // om = conv(offset), 27 ch, NHWC stride 32
    conv_k<64, 27, 32, 0, true, false><<<512, 256, 0, stream>>>(o3, nullptr, aomp, bom, omb, nullptr);
    // align = dcn_core(x, offsets, mask) -> NHWC bf16
    dcn_k<<<512, 256, 0, stream>>>(xtx, omb, adcn, bdcn, align);
    // out = relu(conv(align)) -> NCHW fp32 output 0
    conv_k<64, 64, 64, 2, false, true><<<512, 256, 0, stream>>>(align, nullptr, aout, bout, nullptr, out0);
}

// Round 5
// 237.818 us; speedup vs baseline: 1.0555x; 1.0555x over previous
//
#include <hip/hip_runtime.h>
#include <hip/hip_bf16.h>
#include <math.h>

#define HH 128
#define WW 128
#define HWSZ (HH*WW)

typedef __attribute__((ext_vector_type(8))) short bfrag;   // 8 bf16
typedef __attribute__((ext_vector_type(4))) float f4;

__device__ inline unsigned short f2bf(float v) {
    unsigned u = __builtin_bit_cast(unsigned, v);
    unsigned r = u + 0x7fffu + ((u >> 16) & 1u);
    return (unsigned short)(r >> 16);
}
__device__ inline float bf2f(short s) {
    return __builtin_bit_cast(float, ((unsigned)(unsigned short)s) << 16);
}
__device__ inline float bf2f_lo(unsigned u) { return __builtin_bit_cast(float, u << 16); }
__device__ inline float bf2f_hi(unsigned u) { return __builtin_bit_cast(float, u & 0xffff0000u); }

// ---------------------------------------------------------------------------
// Weight prepack: fp32 W[oc][ic][3][3] -> bf16 A-fragments, K-chunk = 32.
// frag f = ((oct*(NIC/32) + c32)*9 + tap); element = f*512 + lane*8 + j
// oc = oct*16 + (lane&15); ic = c32*32 + (lane>>4)*8 + j
// ---------------------------------------------------------------------------
__device__ inline void pack_frag(const float* __restrict__ w, short* __restrict__ dst,
                                 int i, int NIC, int NOC) {
    int j    = i & 7;
    int lane = (i >> 3) & 63;
    int f    = i >> 9;
    int tap  = f % 9;
    int g    = f / 9;
    int NCH  = NIC >> 5;
    int c32  = g % NCH;
    int oct  = g / NCH;
    int oc   = oct * 16 + (lane & 15);
    int ic   = c32 * 32 + ((lane >> 4) & 3) * 8 + j;
    float v = 0.f;
    if (oc < NOC) v = w[((size_t)oc * NIC + ic) * 9 + tap];
    dst[i] = (short)f2bf(v);
}

#define SZ128 73728
#define SZ64  36864

__global__ void pack_all_k(const float* __restrict__ w1, const float* __restrict__ w2,
                           const float* __restrict__ w3, const float* __restrict__ wom,
                           const float* __restrict__ wout, const float* __restrict__ wdcn,
                           short* __restrict__ ap)
{
    int i = blockIdx.x * 256 + threadIdx.x;
    if      (i < SZ128)                  pack_frag(w1,  ap,                          i,                    128, 64);
    else if (i < 2*SZ128)                pack_frag(w2,  ap + SZ128,                  i - SZ128,            128, 64);
    else if (i < 2*SZ128 + SZ64)         pack_frag(w3,  ap + 2*SZ128,                i - 2*SZ128,           64, 64);
    else if (i < 2*SZ128 + 2*SZ64)       pack_frag(wom, ap + 2*SZ128 + SZ64,         i - 2*SZ128 - SZ64,    64, 27);
    else if (i < 2*SZ128 + 3*SZ64)       pack_frag(wout,ap + 2*SZ128 + 2*SZ64,       i - 2*SZ128 - 2*SZ64,  64, 64);
    else if (i < 2*SZ128 + 4*SZ64)       pack_frag(wdcn,ap + 2*SZ128 + 3*SZ64,       i - 2*SZ128 - 3*SZ64,  64, 64);
}

// ---------------------------------------------------------------------------
// NCHW fp32 -> NHWC bf16 (stride 64), all 3 input tensors in one dispatch.
// ---------------------------------------------------------------------------
__global__ __launch_bounds__(256) void nhwc3_k(const float* __restrict__ x,
                                               const float* __restrict__ xng,
                                               const float* __restrict__ offt,
                                               short* __restrict__ dx,
                                               short* __restrict__ dn,
                                               short* __restrict__ dof)
{
    __shared__ short s_t[128][72];
    const int tid = threadIdx.x;
    const int h = blockIdx.x;
    const int t = blockIdx.y >> 2, b = blockIdx.y & 3;
    const float* src = (t == 0) ? x : (t == 1) ? xng : offt;
    short* dst = (t == 0) ? dx : (t == 1) ? dn : dof;
    for (int i = tid; i < 64 * 128; i += 256) {
        int c = i >> 7, w = i & 127;
        s_t[w][c] = (short)f2bf(src[((size_t)(b * 64 + c)) * HWSZ + h * WW + w]);
    }
    __syncthreads();
    for (int i = tid; i < 128 * 32; i += 256) {
        int w = i >> 5, cp = i & 31;
        unsigned pk = (unsigned)(unsigned short)s_t[w][cp * 2]
                    | ((unsigned)(unsigned short)s_t[w][cp * 2 + 1] << 16);
        *(unsigned*)&dst[(((size_t)(b * 128 + h) * 128 + w) * 64) + cp * 2] = pk;
    }
}

// ---------------------------------------------------------------------------
// MFMA implicit-GEMM 3x3 SAME conv over NHWC bf16, K-chunk = 32.
// R9/R0 harness-verified structure, byte-for-byte (249/251 us pass).
// block = one (b,h) row, 4 waves = 2 oc-halves x 2 px-halves.
// ---------------------------------------------------------------------------
template<int NIC, int NOC, int OCS, int ACT, bool WH, bool WC>
__global__ __launch_bounds__(256, 3) void conv_k(
    const short* __restrict__ in1, const short* __restrict__ in2,
    const short* __restrict__ apack, const float* __restrict__ bias,
    short* __restrict__ outh, float* __restrict__ outc)
{
    constexpr int NCH = NIC / 32;
    __shared__ short s_x[3][130][40];   // [row][px+halo][32ch + pad]

    const int tid  = threadIdx.x;
    const int lane = tid & 63;
    const int wv   = tid >> 6;
    const int wo   = wv & 1;
    const int wp   = wv >> 1;
    const int n16  = lane & 15;
    const int kq   = lane >> 4;

    const int lin = blockIdx.x;                       // 512 blocks
    const int h   = (lin & 7) * 16 + ((lin >> 3) & 15);
    const int b   = lin >> 7;

    f4 acc[2][4];
#pragma unroll
    for (int t = 0; t < 2; ++t)
#pragma unroll
        for (int p = 0; p < 4; ++p) acc[t][p] = (f4){0.f, 0.f, 0.f, 0.f};

    const short* a_lane = apack + (size_t)lane * 8;

    for (int cc = 0; cc < NCH; ++cc) {
        const short* src; int c0;
        if (NIC == 128 && cc >= 2) { src = in2; c0 = (cc - 2) * 32; }
        else                       { src = in1; c0 = cc * 32; }
        __syncthreads();
        // stage 3 rows x 130 px x 32 ch, 16B per thread-iter (R5 verbatim)
        for (int i = tid; i < 1560; i += 256) {
            int row = i / 520, rem = i % 520;
            int px = rem >> 2, q = rem & 3;
            int gy = h - 1 + row, gx = px - 1;
            int4 v = {0, 0, 0, 0};
            if ((unsigned)gy < 128u && (unsigned)gx < 128u)
                v = *(const int4*)&src[(((size_t)(b * 128 + gy)) * 128 + gx) * 64 + c0 + q * 8];
            *(int4*)&s_x[row][px][q * 8] = v;
        }
        __syncthreads();

        if (wo * 32 < NOC) {
            // all-tap A prefetch: 18 independent global loads issued upfront
            bfrag af0[9], af1[9];
#pragma unroll
            for (int tap = 0; tap < 9; ++tap) {
                af0[tap] = *(const bfrag*)(a_lane + (size_t)(((wo * 2 + 0) * NCH + cc) * 9 + tap) * 512);
                af1[tap] = *(const bfrag*)(a_lane + (size_t)(((wo * 2 + 1) * NCH + cc) * 9 + tap) * 512);
            }
#pragma unroll
            for (int tap = 0; tap < 9; ++tap) {
                const int dy = tap / 3, dx = tap % 3;
#pragma unroll
                for (int p = 0; p < 4; ++p) {
                    bfrag bb = *(const bfrag*)&s_x[dy][wp * 64 + p * 16 + n16 + dx][kq * 8];
                    acc[0][p] = __builtin_amdgcn_mfma_f32_16x16x32_bf16(af0[tap], bb, acc[0][p], 0, 0, 0);
                    acc[1][p] = __builtin_amdgcn_mfma_f32_16x16x32_bf16(af1[tap], bb, acc[1][p], 0, 0, 0);
                }
            }
        }
    }

    // epilogue: C/D layout col=lane&15, row=(lane>>4)*4+reg (R5 verbatim)
#pragma unroll
    for (int oct = 0; oct < 2; ++oct) {
        int oc0 = wo * 32 + oct * 16 + kq * 4;
        if (oc0 < NOC) {
            float4 bv = *(const float4*)&bias[oc0];
#pragma unroll
            for (int p = 0; p < 4; ++p) {
                int col = wp * 64 + p * 16 + n16;
                float v0 = acc[oct][p][0] + bv.x;
                float v1 = acc[oct][p][1] + bv.y;
                float v2 = acc[oct][p][2] + bv.z;
                float v3 = acc[oct][p][3] + bv.w;
                if (ACT == 1) {
                    v0 = (v0 >= 0.f) ? v0 : 0.1f * v0;
                    v1 = (v1 >= 0.f) ? v1 : 0.1f * v1;
                    v2 = (v2 >= 0.f) ? v2 : 0.1f * v2;
                    v3 = (v3 >= 0.f) ? v3 : 0.1f * v3;
                }
                if (ACT == 2) {
                    v0 = fmaxf(v0, 0.f); v1 = fmaxf(v1, 0.f);
                    v2 = fmaxf(v2, 0.f); v3 = fmaxf(v3, 0.f);
                }
                if (WH) {
                    uint2 pk;
                    pk.x = (unsigned)f2bf(v0) | ((unsigned)f2bf(v1) << 16);
                    pk.y = (unsigned)f2bf(v2) | ((unsigned)f2bf(v3) << 16);
                    *(uint2*)&outh[(((size_t)(b * 128 + h)) * 128 + col) * OCS + oc0] = pk;
                }
                if (WC) {
                    size_t base = ((size_t)b * NOC) * HWSZ + h * WW + col;
                    outc[base + (size_t)(oc0 + 0) * HWSZ] = v0;
                    outc[base + (size_t)(oc0 + 1) * HWSZ] = v1;
                    outc[base + (size_t)(oc0 + 2) * HWSZ] = v2;
                    outc[base + (size_t)(oc0 + 3) * HWSZ] = v3;
                }
            }
        }
    }
}

// ---------------------------------------------------------------------------
// DCN per-pixel bilinear params from NHWC bf16 om (stride 32), once per px.
// (R0 verbatim)
// ---------------------------------------------------------------------------
__device__ inline void dcn_params(const short* __restrict__ omb, int h, int k, int tid,
                                  float (*s_pw)[4], int (*s_pi)[4])
{
    if (tid < 128) {
        int pix = tid;
        const short* o = omb + pix * 32;
        float oy = bf2f(o[k]);
        float ox = bf2f(o[9 + k]);
        float mv = bf2f(o[18 + k]);
        mv = 1.f / (1.f + expf(-mv));
        float py = (float)(h - 1 + (k / 3)) + oy;
        float px = (float)(pix - 1 + (k % 3)) + ox;
        float y0f = floorf(py), x0f = floorf(px);
        float ly = py - y0f, lx = px - x0f;
        int y0 = (int)y0f, x0 = (int)x0f;
        int y1 = y0 + 1, x1 = x0 + 1;
        float v00 = ((unsigned)y0 < 128u && (unsigned)x0 < 128u) ? 1.f : 0.f;
        float v01 = ((unsigned)y0 < 128u && (unsigned)x1 < 128u) ? 1.f : 0.f;
        float v10 = ((unsigned)y1 < 128u && (unsigned)x0 < 128u) ? 1.f : 0.f;
        float v11 = ((unsigned)y1 < 128u && (unsigned)x1 < 128u) ? 1.f : 0.f;
        int yc0 = min(max(y0, 0), 127), yc1 = min(max(y1, 0), 127);
        int xc0 = min(max(x0, 0), 127), xc1 = min(max(x1, 0), 127);
        s_pw[pix][0] = (1.f - ly) * (1.f - lx) * mv * v00;
        s_pw[pix][1] = (1.f - ly) * lx * mv * v01;
        s_pw[pix][2] = ly * (1.f - lx) * mv * v10;
        s_pw[pix][3] = ly * lx * mv * v11;
        s_pi[pix][0] = (yc0 * WW + xc0) * 64;
        s_pi[pix][1] = (yc0 * WW + xc1) * 64;
        s_pi[pix][2] = (yc1 * WW + xc0) * 64;
        s_pi[pix][3] = (yc1 * WW + xc1) * 64;
    }
}

// ---------------------------------------------------------------------------
// MFMA DCN (R0 structure: block = full row, 256 thr, wo x wp waves).
// R10: single-variable change vs green R9 — sampling-loop unroll 4 -> 8 and
// launch_bounds (256,4) -> (256,2). Rationale: FETCH=7.4MB shows gathers take
// compulsory HBM misses (~900cy); unroll 8 doubles in-flight gathers per
// thread (2 stall groups per k instead of 4). VGPR cap 128 -> 256 is free:
// occupancy is grid-limited at 2 blocks/CU (512 blocks / 256 CU) regardless.
// Per-pixel FP accumulation order unchanged (each pixel = one thread-iter).
// ---------------------------------------------------------------------------
__global__ __launch_bounds__(256, 2) void dcn_k(
    const short* __restrict__ xt, const short* __restrict__ om,
    const short* __restrict__ adcn, const float* __restrict__ bias,
    short* __restrict__ outh)
{
    __shared__ short s_samp[128][72];
    __shared__ float s_pw[128][4];
    __shared__ int   s_pi[128][4];

    const int tid  = threadIdx.x;
    const int lane = tid & 63;
    const int wv   = tid >> 6;
    const int wo   = wv & 1;
    const int wp   = wv >> 1;
    const int n16  = lane & 15;
    const int kq   = lane >> 4;

    const int lin = blockIdx.x;                       // 512 blocks
    const int h   = (lin & 7) * 16 + ((lin >> 3) & 15);
    const int b   = lin >> 7;

    f4 acc[2][4];
#pragma unroll
    for (int t = 0; t < 2; ++t)
#pragma unroll
        for (int p = 0; p < 4; ++p) acc[t][p] = (f4){0.f, 0.f, 0.f, 0.f};

    const short* a_lane = adcn + (size_t)lane * 8;
    const short* xb  = xt + (size_t)b * HWSZ * 64;
    const short* omb = om + ((size_t)(b * 128 + h)) * 128 * 32;

    dcn_params(omb, h, 0, tid, s_pw, s_pi);

    const int pp = lane >> 5;      // pixel-pair half
    const int cp = lane & 31;      // channel pair

    bfrag a_cur[2][2], a_nxt[2][2];      // [oi][ks]
#pragma unroll
    for (int oi = 0; oi < 2; ++oi)
#pragma unroll
        for (int ks = 0; ks < 2; ++ks)
            a_cur[oi][ks] = *(const bfrag*)(a_lane +
                (size_t)(((wo * 2 + oi) * 2 + ks) * 9 + 0) * 512);

    for (int k = 0; k < 9; ++k) {
        __syncthreads();   // params(k) visible; MFMA(k-1) done with s_samp
#pragma unroll 8
        for (int i = 0; i < 16; ++i) {
            int pix = i * 8 + wv * 2 + pp;
            float4 w = *(const float4*)s_pw[pix];
            int4  ix = *(const int4*)s_pi[pix];
            unsigned u00 = *(const unsigned*)&xb[ix.x + cp * 2];
            unsigned u01 = *(const unsigned*)&xb[ix.y + cp * 2];
            unsigned u10 = *(const unsigned*)&xb[ix.z + cp * 2];
            unsigned u11 = *(const unsigned*)&xb[ix.w + cp * 2];
            float lo = w.x * bf2f_lo(u00) + w.y * bf2f_lo(u01) + w.z * bf2f_lo(u10) + w.w * bf2f_lo(u11);
            float hi = w.x * bf2f_hi(u00) + w.y * bf2f_hi(u01) + w.z * bf2f_hi(u10) + w.w * bf2f_hi(u11);
            *(unsigned*)&s_samp[pix][cp * 2] = (unsigned)f2bf(lo) | ((unsigned)f2bf(hi) << 16);
        }
        __syncthreads();
        if (k < 8) {
            dcn_params(omb, h, k + 1, tid, s_pw, s_pi);
#pragma unroll
            for (int oi = 0; oi < 2; ++oi)
#pragma unroll
                for (int ks = 0; ks < 2; ++ks)
                    a_nxt[oi][ks] = *(const bfrag*)(a_lane +
                        (size_t)(((wo * 2 + oi) * 2 + ks) * 9 + (k + 1)) * 512);
        }
#pragma unroll
        for (int ks = 0; ks < 2; ++ks) {
#pragma unroll
            for (int p = 0; p < 4; ++p) {
                bfrag bb = *(const bfrag*)&s_samp[wp * 64 + p * 16 + n16][ks * 32 + kq * 8];
                acc[0][p] = __builtin_amdgcn_mfma_f32_16x16x32_bf16(a_cur[0][ks], bb, acc[0][p], 0, 0, 0);
                acc[1][p] = __builtin_amdgcn_mfma_f32_16x16x32_bf16(a_cur[1][ks], bb, acc[1][p], 0, 0, 0);
            }
        }
#pragma unroll
        for (int oi = 0; oi < 2; ++oi)
#pragma unroll
            for (int ks = 0; ks < 2; ++ks)
                a_cur[oi][ks] = a_nxt[oi][ks];
    }

    // epilogue: NHWC bf16, stride 64, no activation (R0 verbatim)
#pragma unroll
    for (int oct = 0; oct < 2; ++oct) {
        int oc0 = wo * 32 + oct * 16 + kq * 4;
        float4 bv = *(const float4*)&bias[oc0];
#pragma unroll
        for (int p = 0; p < 4; ++p) {
            int col = wp * 64 + p * 16 + n16;
            uint2 pk;
            pk.x = (unsigned)f2bf(acc[oct][p][0] + bv.x) | ((unsigned)f2bf(acc[oct][p][1] + bv.y) << 16);
            pk.y = (unsigned)f2bf(acc[oct][p][2] + bv.z) | ((unsigned)f2bf(acc[oct][p][3] + bv.w) << 16);
            *(uint2*)&outh[(((size_t)(b * 128 + h)) * 128 + col) * 64 + oc0] = pk;
        }
    }
}

// ---------------------------------------------------------------------------
extern "C" void kernel_launch(void* const* d_in, const int* in_sizes, int n_in,
                              void* d_out, int out_size, void* d_ws, size_t ws_size,
                              hipStream_t stream)
{
    const float* x      = (const float*)d_in[0];
    const float* xng    = (const float*)d_in[1];
    const float* offt   = (const float*)d_in[2];
    const float* w1     = (const float*)d_in[3];
    const float* b1     = (const float*)d_in[4];
    const float* w2     = (const float*)d_in[5];
    const float* b2     = (const float*)d_in[6];
    const float* w3     = (const float*)d_in[7];
    const float* b3     = (const float*)d_in[8];
    const float* wom    = (const float*)d_in[9];
    const float* bom    = (const float*)d_in[10];
    const float* wdcn   = (const float*)d_in[11];
    const float* bdcn   = (const float*)d_in[12];
    const float* wout   = (const float*)d_in[13];
    const float* bout   = (const float*)d_in[14];

    float* out0 = (float*)d_out;
    float* out1 = out0 + (size_t)4 * 64 * HWSZ;

    const size_t NB = (size_t)4 * HWSZ * 64;   // elements per NHWC bf16 tensor
    short* xtx = (short*)d_ws;        // x NHWC (conv1 + dcn)
    short* xtn = xtx + NB;            // x_neigh NHWC -> later o2 -> later align
    short* xto = xtn + NB;            // offset_t NHWC -> later om (stride 32)
    short* o1  = xto + NB;            // offset_1 -> later o3
    short* apk = o1 + NB;

    short* o2    = xtn;
    short* o3    = o1;
    short* omb   = xto;
    short* align = xtn;

    short* a1p  = apk;
    short* a2p  = apk + SZ128;
    short* a3p  = apk + 2 * SZ128;
    short* aomp = apk + 2 * SZ128 + SZ64;
    short* aout = apk + 2 * SZ128 + 2 * SZ64;
    short* adcn = apk + 2 * SZ128 + 3 * SZ64;

    pack_all_k<<<(2 * SZ128 + 4 * SZ64 + 255) / 256, 256, 0, stream>>>(
        w1, w2, w3, wom, wout, wdcn, apk);
    nhwc3_k<<<dim3(HH, 12), 256, 0, stream>>>(x, xng, offt, xtx, xtn, xto);

    // offset_1 = lrelu(conv(cat(x, x_neigh)))
    conv_k<128, 64, 64, 1, true, false><<<512, 256, 0, stream>>>(xtx, xtn, a1p, b1, o1, nullptr);
    // offset_2 = lrelu(conv(cat(offset_1, offset_t)))
    conv_k<128, 64, 64, 1, true, false><<<512, 256, 0, stream>>>(o1, xto, a2p, b2, o2, nullptr);
    // offset = lrelu(conv(offset_2)) -> NHWC for conv4 + NCHW fp32 output 1
    conv_k<64, 64, 64, 1, true, true><<<512, 256, 0, stream>>>(o2, nullptr, a3p, b3, o3, out1);
    // om = conv(offset), 27 ch, NHWC stride 32
    conv_k<64, 27, 32, 0, true, false><<<512, 256, 0, stream>>>(o3, nullptr, aomp, bom, omb, nullptr);
    // align = dcn_core(x, offsets, mask) -> NHWC bf16
    dcn_k<<<512, 256, 0, stream>>>(xtx, omb, adcn, bdcn, align);
    // out = relu(conv(align)) -> NCHW fp32 output 0
    conv_k<64, 64, 64, 2, false, true><<<512, 256, 0, stream>>>(align, nullptr, aout, bout, nullptr, out0);
}